// Round 2
// baseline (972.579 us; speedup 1.0000x reference)
//
#include <hip/hip_runtime.h>

#define E 100

// ---------------------------------------------------------------------------
// Level 0+1 fused: leaf embedding gather + leaf projections + level-1 combine.
// SPLIT=4 lanes per node, each lane computes 25 of the 100 outputs.
// Node outputs staged in LDS, then written to h1 as coalesced float4.
// ---------------------------------------------------------------------------
__global__ __launch_bounds__(256) void leaf_l1_kernel(
    const int* __restrict__ word_ids, const float* __restrict__ emb,
    const float* __restrict__ Wl, const float* __restrict__ bl,
    const float* __restrict__ Wp, const float* __restrict__ bp,
    float* __restrict__ h1, float* __restrict__ out) {
  __shared__ float sh[64 * E];          // 25.6 KB
  const int tid = threadIdx.x;
  const int gt = blockIdx.x * 256 + tid;
  const int node = gt >> 2;             // global node (65536 total)
  const int k = tid & 3;                // output quarter
  const int node_l = tid >> 2;          // 0..63

  const float4* A4 = (const float4*)(emb + (size_t)word_ids[2 * node] * E);
  const float4* B4 = (const float4*)(emb + (size_t)word_ids[2 * node + 1] * E);
  const float4* Wl4 = (const float4*)Wl;
  const float4* Wp4 = (const float4*)Wp;

  float acc[25];
  #pragma unroll
  for (int o = 0; o < 25; ++o) acc[o] = 2.0f * bl[k * 25 + o];
  float lp0 = bp[0], lp1 = bp[1];       // leaf projection (lanes k=0,1 use it)

  #pragma unroll 1
  for (int q = 0; q < 25; ++q) {
    float4 a = A4[q], b = B4[q];
    float4 s4;
    s4.x = a.x + b.x; s4.y = a.y + b.y; s4.z = a.z + b.z; s4.w = a.w + b.w;
    float4 m = (k & 1) ? b : a;         // leaf k's own embedding row
    float4 wp0 = Wp4[q], wp1 = Wp4[25 + q];
    lp0 = fmaf(m.x, wp0.x, lp0); lp0 = fmaf(m.y, wp0.y, lp0);
    lp0 = fmaf(m.z, wp0.z, lp0); lp0 = fmaf(m.w, wp0.w, lp0);
    lp1 = fmaf(m.x, wp1.x, lp1); lp1 = fmaf(m.y, wp1.y, lp1);
    lp1 = fmaf(m.z, wp1.z, lp1); lp1 = fmaf(m.w, wp1.w, lp1);
    #pragma unroll
    for (int o = 0; o < 25; ++o) {
      float4 w = Wl4[(k * 25 + o) * 25 + q];
      acc[o] = fmaf(s4.x, w.x, acc[o]);
      acc[o] = fmaf(s4.y, w.y, acc[o]);
      acc[o] = fmaf(s4.z, w.z, acc[o]);
      acc[o] = fmaf(s4.w, w.w, acc[o]);
    }
  }

  // epilogue: relu, stage to LDS, projection partials
  float pj0 = 0.0f, pj1 = 0.0f;
  #pragma unroll
  for (int o = 0; o < 25; ++o) {
    int ep = k * 25 + o;
    float v = fmaxf(acc[o], 0.0f);
    sh[node_l * E + ep] = v;
    pj0 = fmaf(v, Wp[ep], pj0);
    pj1 = fmaf(v, Wp[E + ep], pj1);
  }

  // leaf outputs (level 0): pos = 2*li - popc(li)
  if (k < 2) {
    int li = 2 * node + k;
    int posl = 2 * li - __popc(li);
    out[2 * posl]     = lp0;
    out[2 * posl + 1] = lp1;
  }

  // reduce projection over the node's 4 lanes
  pj0 += __shfl_xor(pj0, 1, 64); pj0 += __shfl_xor(pj0, 2, 64);
  pj1 += __shfl_xor(pj1, 1, 64); pj1 += __shfl_xor(pj1, 2, 64);
  if (k == 0) {
    int pos = ((node + 1) << 2) - 2 - __popc(node);   // level 1
    out[2 * pos]     = pj0 + bp[0];
    out[2 * pos + 1] = pj1 + bp[1];
  }

  __syncthreads();
  // coalesced float4 write of 64 nodes x 100 floats
  const float4* sh4 = (const float4*)sh;
  float4* dst4 = (float4*)(h1 + (size_t)blockIdx.x * 64 * E);
  #pragma unroll
  for (int t = tid; t < 64 * 25; t += 256) dst4[t] = sh4[t];
}

// ---------------------------------------------------------------------------
// Generic level combine: SPLIT lanes per node, LDS-staged coalesced h writes.
// Grids are exact multiples of nodes-per-block (no guards needed).
// ---------------------------------------------------------------------------
template<int SPLIT>
__global__ __launch_bounds__(256) void combine_kernel(
    const float* __restrict__ hsrc, float* __restrict__ hdst,
    const float* __restrict__ Wl, const float* __restrict__ bl,
    const float* __restrict__ Wp, const float* __restrict__ bp,
    float* __restrict__ out, int lvl) {
  constexpr int NPB = 256 / SPLIT;                 // nodes per block
  constexpr int TO  = (E + SPLIT - 1) / SPLIT;     // outputs per lane
  __shared__ float sh[NPB * E];
  const int tid = threadIdx.x;
  const int gt = blockIdx.x * 256 + tid;
  const int node = gt / SPLIT;
  const int k = tid % SPLIT;
  const int node_l = tid / SPLIT;

  const float4* S4  = (const float4*)hsrc;          // children contiguous: node*200 floats
  const float4* Wl4 = (const float4*)Wl;

  float acc[TO];
  #pragma unroll
  for (int o = 0; o < TO; ++o) {
    int ep = k * TO + o;
    acc[o] = (ep < E) ? 2.0f * bl[ep] : 0.0f;
  }

  #pragma unroll 1
  for (int q = 0; q < 25; ++q) {
    float4 a = S4[node * 50 + q];
    float4 b = S4[node * 50 + 25 + q];
    float4 s4;
    s4.x = a.x + b.x; s4.y = a.y + b.y; s4.z = a.z + b.z; s4.w = a.w + b.w;
    #pragma unroll
    for (int o = 0; o < TO; ++o) {
      int ep = k * TO + o;
      if (ep < E) {
        float4 w = Wl4[ep * 25 + q];
        acc[o] = fmaf(s4.x, w.x, acc[o]);
        acc[o] = fmaf(s4.y, w.y, acc[o]);
        acc[o] = fmaf(s4.z, w.z, acc[o]);
        acc[o] = fmaf(s4.w, w.w, acc[o]);
      }
    }
  }

  float pj0 = 0.0f, pj1 = 0.0f;
  #pragma unroll
  for (int o = 0; o < TO; ++o) {
    int ep = k * TO + o;
    if (ep < E) {
      float v = fmaxf(acc[o], 0.0f);
      sh[node_l * E + ep] = v;
      pj0 = fmaf(v, Wp[ep], pj0);
      pj1 = fmaf(v, Wp[E + ep], pj1);
    }
  }

  #pragma unroll
  for (int d = SPLIT >> 1; d > 0; d >>= 1) {
    pj0 += __shfl_xor(pj0, d, 64);
    pj1 += __shfl_xor(pj1, d, 64);
  }
  if (k == 0) {
    int pos = ((node + 1) << (lvl + 1)) - 2 - __popc(node);
    out[2 * pos]     = pj0 + bp[0];
    out[2 * pos + 1] = pj1 + bp[1];
  }

  __syncthreads();
  const float4* sh4 = (const float4*)sh;
  float4* dst4 = (float4*)(hdst + (size_t)blockIdx.x * NPB * E);
  #pragma unroll
  for (int t = tid; t < NPB * 25; t += 256) dst4[t] = sh4[t];
}

// ---------------------------------------------------------------------------
// Levels 12..17 (32 -> 1 nodes) in one block, LDS-resident ping-pong.
// 16 lanes per node, 7 outputs per lane (112 covers 100).
// ---------------------------------------------------------------------------
__global__ __launch_bounds__(512) void top_kernel(
    const float* __restrict__ h11,
    const float* __restrict__ Wl, const float* __restrict__ bl,
    const float* __restrict__ Wp, const float* __restrict__ bp,
    float* __restrict__ out) {
  __shared__ float bufA[64 * E];   // 25.6 KB
  __shared__ float bufB[32 * E];   // 12.8 KB
  const int tid = threadIdx.x;     // 512 threads
  const float4* Wl4 = (const float4*)Wl;
  for (int f = tid; f < 64 * E; f += 512) bufA[f] = h11[f];
  __syncthreads();
  float* c = bufA;
  float* x = bufB;
  int n = 32;
  for (int lvl = 12; lvl <= 17; ++lvl, n >>= 1) {
    int nn = tid >> 4;
    int k  = tid & 15;
    float pj0 = 0.0f, pj1 = 0.0f;
    if (nn < n) {
      float acc[7];
      #pragma unroll
      for (int o = 0; o < 7; ++o) {
        int ep = k * 7 + o;
        acc[o] = (ep < E) ? 2.0f * bl[ep] : 0.0f;
      }
      const float4* c4 = (const float4*)(c + nn * (2 * E));
      #pragma unroll 1
      for (int q = 0; q < 25; ++q) {
        float4 a = c4[q], b = c4[q + 25];
        float4 s4;
        s4.x = a.x + b.x; s4.y = a.y + b.y; s4.z = a.z + b.z; s4.w = a.w + b.w;
        #pragma unroll
        for (int o = 0; o < 7; ++o) {
          int ep = k * 7 + o;
          if (ep < E) {
            float4 w = Wl4[ep * 25 + q];
            acc[o] = fmaf(s4.x, w.x, acc[o]);
            acc[o] = fmaf(s4.y, w.y, acc[o]);
            acc[o] = fmaf(s4.z, w.z, acc[o]);
            acc[o] = fmaf(s4.w, w.w, acc[o]);
          }
        }
      }
      #pragma unroll
      for (int o = 0; o < 7; ++o) {
        int ep = k * 7 + o;
        if (ep < E) {
          float v = fmaxf(acc[o], 0.0f);
          x[nn * E + ep] = v;
          pj0 = fmaf(v, Wp[ep], pj0);
          pj1 = fmaf(v, Wp[E + ep], pj1);
        }
      }
    }
    #pragma unroll
    for (int d = 8; d > 0; d >>= 1) {
      pj0 += __shfl_xor(pj0, d, 64);
      pj1 += __shfl_xor(pj1, d, 64);
    }
    if (nn < n && k == 0) {
      int pos = ((nn + 1) << (lvl + 1)) - 2 - __popc(nn);
      out[2 * pos]     = pj0 + bp[0];
      out[2 * pos + 1] = pj1 + bp[1];
    }
    __syncthreads();
    float* t = c; c = x; x = t;
  }
}

extern "C" void kernel_launch(void* const* d_in, const int* in_sizes, int n_in,
                              void* d_out, int out_size, void* d_ws, size_t ws_size,
                              hipStream_t stream) {
  const int*   word_ids = (const int*)  d_in[0];
  const float* emb      = (const float*)d_in[1];
  const float* Wl       = (const float*)d_in[2];
  const float* bl       = (const float*)d_in[3];
  const float* Wp       = (const float*)d_in[4];
  const float* bp       = (const float*)d_in[5];
  float* out = (float*)d_out;

  float* hOdd  = (float*)d_ws;                  // levels 1,3,5,... (max 65536 nodes)
  float* hEven = hOdd + (size_t)65536 * E;      // levels 2,4,...   (max 32768 nodes)

  // level 0 (leaves) + level 1 fused: 65536 nodes x 4 lanes = 1024 blocks
  leaf_l1_kernel<<<1024, 256, 0, stream>>>(word_ids, emb, Wl, bl, Wp, bp, hOdd, out);

  const float* src = hOdd;
  for (int lvl = 2; lvl <= 11; ++lvl) {
    int n = 1 << (17 - lvl);
    float* dst = (lvl & 1) ? hOdd : hEven;
    if (lvl <= 7) {
      // SPLIT=4: 64 nodes/block
      combine_kernel<4><<<n / 64, 256, 0, stream>>>(src, dst, Wl, bl, Wp, bp, out, lvl);
    } else {
      // SPLIT=8: 32 nodes/block
      combine_kernel<8><<<n / 32, 256, 0, stream>>>(src, dst, Wl, bl, Wp, bp, out, lvl);
    }
    src = dst;
  }

  // levels 12..17 in one block (src = level-11 buffer = hOdd)
  top_kernel<<<1, 512, 0, stream>>>(src, Wl, bl, Wp, bp, out);
}

// Round 3
// 362.578 us; speedup vs baseline: 2.6824x; 2.6824x over previous
//
#include <hip/hip_runtime.h>

#define E 100

// ws layout (floats): hOdd [0, 6553600) | hEven [6553600, 9830400) | WlT2 [9830400, 9840400)
// WlT2[(e/2)*200 + ep*2 + (e&1)] = Wl[ep*E + e]  (e-major, pair-interleaved)

__global__ void prep_kernel(const float* __restrict__ Wl, float* __restrict__ WlT2) {
  int i = blockIdx.x * 256 + threadIdx.x;
  if (i < E * E) {
    int e = i / E, ep = i % E;
    WlT2[(e >> 1) * (2 * E) + ep * 2 + (e & 1)] = Wl[ep * E + e];
  }
}

// ---------------------------------------------------------------------------
// Leaf + level-1 fused. 64 level-1 nodes (=128 leaves) per block.
// lane = node, wave = output chunk (uniform), w via scalar loads from WlT2.
// ---------------------------------------------------------------------------
__global__ __launch_bounds__(256) void leaf_kernel(
    const int* __restrict__ word_ids, const float* __restrict__ emb,
    const float* __restrict__ WlT2, const float* __restrict__ bl,
    const float* __restrict__ Wp, const float* __restrict__ bp,
    float* __restrict__ h1, float* __restrict__ out) {
  __shared__ float L[128 * 101];     // 51.7 KB, leaf rows, pad 101
  __shared__ float PJ[4][64][2];
  __shared__ int wid[128];
  const int tid = threadIdx.x;
  const int lane = tid & 63;
  const int wave = __builtin_amdgcn_readfirstlane(tid >> 6);
  const int base = wave * 25;        // uniform output-chunk base

  if (tid < 128) wid[tid] = word_ids[blockIdx.x * 128 + tid];
  __syncthreads();

  // gather 128 leaf embedding rows -> LDS
  for (int i = tid; i < 128 * 25; i += 256) {
    int lf = i / 25, q = i % 25;
    const float4* r4 = (const float4*)(emb + (size_t)wid[lf] * E);
    float4 v = r4[q];
    int o = lf * 101 + q * 4;
    L[o] = v.x; L[o + 1] = v.y; L[o + 2] = v.z; L[o + 3] = v.w;
  }
  __syncthreads();

  // leaf projections: waves 0,1 cover 128 leaves, lane = leaf
  if (wave < 2) {
    int lf = wave * 64 + lane;
    const float* lr = L + lf * 101;
    float p0 = bp[0], p1 = bp[1];
    for (int e = 0; e < E; ++e) {
      float x = lr[e];
      p0 = fmaf(x, Wp[e], p0);       // Wp[e] uniform -> s_load
      p1 = fmaf(x, Wp[E + e], p1);
    }
    int li = blockIdx.x * 128 + lf;
    int posl = 2 * li - __popc(li);
    out[2 * posl]     = p0;
    out[2 * posl + 1] = p1;
  }

  // level-1 combine: node = lane, outputs [base, base+25)
  float acc[25];
  #pragma unroll
  for (int o = 0; o < 25; ++o) acc[o] = 2.0f * bl[base + o];
  const float* r0 = L + (2 * lane) * 101;
  const float* r1 = L + (2 * lane + 1) * 101;
  for (int eb = 0; eb < 50; ++eb) {
    float s0 = r0[2 * eb]     + r1[2 * eb];
    float s1 = r0[2 * eb + 1] + r1[2 * eb + 1];
    const float* w = WlT2 + eb * 200 + base * 2;   // uniform -> s_load x50 floats
    #pragma unroll
    for (int o = 0; o < 25; ++o) {
      acc[o] = fmaf(s0, w[2 * o],     acc[o]);
      acc[o] = fmaf(s1, w[2 * o + 1], acc[o]);
    }
  }
  float pj0 = 0.f, pj1 = 0.f;
  #pragma unroll
  for (int o = 0; o < 25; ++o) {
    float v = fmaxf(acc[o], 0.f);
    acc[o] = v;
    pj0 = fmaf(v, Wp[base + o], pj0);
    pj1 = fmaf(v, Wp[E + base + o], pj1);
  }
  PJ[wave][lane][0] = pj0; PJ[wave][lane][1] = pj1;
  __syncthreads();
  // reuse L front as out-tile [64][101]
  #pragma unroll
  for (int o = 0; o < 25; ++o) L[lane * 101 + base + o] = acc[o];
  if (tid < 64) {
    float p0 = PJ[0][tid][0] + PJ[1][tid][0] + PJ[2][tid][0] + PJ[3][tid][0] + bp[0];
    float p1 = PJ[0][tid][1] + PJ[1][tid][1] + PJ[2][tid][1] + PJ[3][tid][1] + bp[1];
    int node = blockIdx.x * 64 + tid;
    int pos = ((node + 1) << 2) - 2 - __popc(node);
    out[2 * pos]     = p0;
    out[2 * pos + 1] = p1;
  }
  __syncthreads();
  float* dst = h1 + (size_t)blockIdx.x * 64 * E;
  for (int i = tid; i < 64 * E; i += 256) dst[i] = L[(i / E) * 101 + (i % E)];
}

// ---------------------------------------------------------------------------
// Generic combine, levels 2..11. 64 nodes/block.
// ---------------------------------------------------------------------------
__global__ __launch_bounds__(256) void combine_kernel(
    const float* __restrict__ hsrc, float* __restrict__ hdst,
    const float* __restrict__ WlT2, const float* __restrict__ bl,
    const float* __restrict__ Wp, const float* __restrict__ bp,
    float* __restrict__ out, int lvl) {
  __shared__ float S[64 * 101];      // 25.9 KB
  __shared__ float PJ[4][64][2];
  const int tid = threadIdx.x;
  const int lane = tid & 63;
  const int wave = __builtin_amdgcn_readfirstlane(tid >> 6);
  const int base = wave * 25;

  // stage S = left + right (children rows contiguous)
  const float4* src4 = (const float4*)(hsrc + (size_t)blockIdx.x * 64 * 2 * E);
  for (int i = tid; i < 64 * 25; i += 256) {
    int n = i / 25, q = i % 25;
    float4 a = src4[n * 50 + q];
    float4 b = src4[n * 50 + 25 + q];
    int o = n * 101 + q * 4;
    S[o]     = a.x + b.x;
    S[o + 1] = a.y + b.y;
    S[o + 2] = a.z + b.z;
    S[o + 3] = a.w + b.w;
  }
  __syncthreads();

  float acc[25];
  #pragma unroll
  for (int o = 0; o < 25; ++o) acc[o] = 2.0f * bl[base + o];
  const float* srow = S + lane * 101;
  for (int eb = 0; eb < 50; ++eb) {
    float s0 = srow[2 * eb];
    float s1 = srow[2 * eb + 1];
    const float* w = WlT2 + eb * 200 + base * 2;
    #pragma unroll
    for (int o = 0; o < 25; ++o) {
      acc[o] = fmaf(s0, w[2 * o],     acc[o]);
      acc[o] = fmaf(s1, w[2 * o + 1], acc[o]);
    }
  }
  float pj0 = 0.f, pj1 = 0.f;
  #pragma unroll
  for (int o = 0; o < 25; ++o) {
    float v = fmaxf(acc[o], 0.f);
    acc[o] = v;
    pj0 = fmaf(v, Wp[base + o], pj0);
    pj1 = fmaf(v, Wp[E + base + o], pj1);
  }
  PJ[wave][lane][0] = pj0; PJ[wave][lane][1] = pj1;
  __syncthreads();
  #pragma unroll
  for (int o = 0; o < 25; ++o) S[lane * 101 + base + o] = acc[o];
  if (tid < 64) {
    float p0 = PJ[0][tid][0] + PJ[1][tid][0] + PJ[2][tid][0] + PJ[3][tid][0] + bp[0];
    float p1 = PJ[0][tid][1] + PJ[1][tid][1] + PJ[2][tid][1] + PJ[3][tid][1] + bp[1];
    int node = blockIdx.x * 64 + tid;
    int pos = ((node + 1) << (lvl + 1)) - 2 - __popc(node);
    out[2 * pos]     = p0;
    out[2 * pos + 1] = p1;
  }
  __syncthreads();
  float* dst = hdst + (size_t)blockIdx.x * 64 * E;
  for (int i = tid; i < 64 * E; i += 256) dst[i] = S[(i / E) * 101 + (i % E)];
}

// ---------------------------------------------------------------------------
// Levels 12..17 fused in one block, LDS ping-pong, same compute structure.
// ---------------------------------------------------------------------------
__global__ __launch_bounds__(256) void top_kernel(
    const float* __restrict__ h11, const float* __restrict__ WlT2,
    const float* __restrict__ bl, const float* __restrict__ Wp,
    const float* __restrict__ bp, float* __restrict__ out) {
  __shared__ float A[64 * 101];
  __shared__ float B[64 * 101];
  __shared__ float PJ[4][64][2];
  const int tid = threadIdx.x;
  const int lane = tid & 63;
  const int wave = __builtin_amdgcn_readfirstlane(tid >> 6);
  const int base = wave * 25;
  for (int i = tid; i < 64 * E; i += 256) A[(i / E) * 101 + (i % E)] = h11[i];
  __syncthreads();
  int n = 32;
  for (int lvl = 12; lvl <= 17; ++lvl, n >>= 1) {
    for (int i = tid; i < n * E; i += 256) {
      int nd = i / E, e = i % E;
      B[nd * 101 + e] = A[(2 * nd) * 101 + e] + A[(2 * nd + 1) * 101 + e];
    }
    __syncthreads();
    float acc[25];
    #pragma unroll
    for (int o = 0; o < 25; ++o) acc[o] = 2.0f * bl[base + o];
    const float* srow = B + lane * 101;
    if (lane < n) {
      for (int eb = 0; eb < 50; ++eb) {
        float s0 = srow[2 * eb], s1 = srow[2 * eb + 1];
        const float* w = WlT2 + eb * 200 + base * 2;
        #pragma unroll
        for (int o = 0; o < 25; ++o) {
          acc[o] = fmaf(s0, w[2 * o],     acc[o]);
          acc[o] = fmaf(s1, w[2 * o + 1], acc[o]);
        }
      }
    }
    float pj0 = 0.f, pj1 = 0.f;
    #pragma unroll
    for (int o = 0; o < 25; ++o) {
      float v = fmaxf(acc[o], 0.f);
      acc[o] = v;
      pj0 = fmaf(v, Wp[base + o], pj0);
      pj1 = fmaf(v, Wp[E + base + o], pj1);
    }
    PJ[wave][lane][0] = pj0; PJ[wave][lane][1] = pj1;
    __syncthreads();
    if (lane < n) {
      #pragma unroll
      for (int o = 0; o < 25; ++o) A[lane * 101 + base + o] = acc[o];
    }
    if (tid < n) {
      float p0 = PJ[0][tid][0] + PJ[1][tid][0] + PJ[2][tid][0] + PJ[3][tid][0] + bp[0];
      float p1 = PJ[0][tid][1] + PJ[1][tid][1] + PJ[2][tid][1] + PJ[3][tid][1] + bp[1];
      int pos = ((tid + 1) << (lvl + 1)) - 2 - __popc(tid);
      out[2 * pos]     = p0;
      out[2 * pos + 1] = p1;
    }
    __syncthreads();
  }
}

extern "C" void kernel_launch(void* const* d_in, const int* in_sizes, int n_in,
                              void* d_out, int out_size, void* d_ws, size_t ws_size,
                              hipStream_t stream) {
  const int*   word_ids = (const int*)  d_in[0];
  const float* emb      = (const float*)d_in[1];
  const float* Wl       = (const float*)d_in[2];
  const float* bl       = (const float*)d_in[3];
  const float* Wp       = (const float*)d_in[4];
  const float* bp       = (const float*)d_in[5];
  float* out = (float*)d_out;

  float* hOdd  = (float*)d_ws;                  // levels 1,3,5,... (max 65536 rows)
  float* hEven = hOdd + (size_t)6553600;        // levels 2,4,...   (max 32768 rows)
  float* WlT2  = hOdd + (size_t)9830400;        // 10000 floats

  prep_kernel<<<40, 256, 0, stream>>>(Wl, WlT2);
  leaf_kernel<<<1024, 256, 0, stream>>>(word_ids, emb, WlT2, bl, Wp, bp, hOdd, out);

  const float* src = hOdd;
  for (int lvl = 2; lvl <= 11; ++lvl) {
    int n = 1 << (17 - lvl);
    float* dst = (lvl & 1) ? hOdd : hEven;
    combine_kernel<<<n / 64, 256, 0, stream>>>(src, dst, WlT2, bl, Wp, bp, out, lvl);
    src = dst;
  }

  top_kernel<<<1, 256, 0, stream>>>(src, WlT2, bl, Wp, bp, out);
}